// Round 11
// baseline (101.966 us; speedup 1.0000x reference)
//
#include <hip/hip_runtime.h>
#include <math.h>

// Adder2D: out[n,co,h,w] = -sum_{ci,kh,kw} |x[n,ci,h+kh-1,w+kw-1] - w[co,ci,kh,kw]|
// x: [16,64,32,32] f32, w: [64,64,3,3] f32, out: [16,64,32,32] f32, pad=1 stride=1.
//
// R12: batch SMEM consumption per-ROUND. R11 post-mortem: scalarization
// worked (SGPR 112) and LW=35 killed bank conflicts (2.05M->147K) but dur
// stayed 47.7us: gfx9 SMEM completes OUT OF ORDER, so consuming any s_load
// needs lgkmcnt(0), which drains all outstanding ds_reads (shared counter).
// Per-ci w-loads => 16 full drains/kernel, convoying 8 barrier-locked waves.
// Now: 8-way ci split (CPG=2), PX=4 px/thread. 512-thr block = 64 output
// threads x 8 groups; per round ONE batched s_load of 72 floats (2 ci
// slices) -> ONE drain per round (4/kernel). The 2x288-VALU compute block
// is then pure {counted-lgkmcnt ds_read + VALU}, freely pipelined by the
// compiler. LDS pipe ~empty; VALU floor (15.4us) dominant.
// Layout: LW=35 (proven conflict-free), x reads scalar b32 (<=2-way).
// Reduction: 7 partials, stride-20 slots (float4-aligned), once/kernel.

#define N_   16
#define CI_  64
#define CO_  64
#define HW_  32
#define CG   4      // co per thread (= all of COB)
#define COB  4      // co per block
#define PX   4      // pixels per thread
#define RG   8      // pixel rows per block
#define CIC  16     // ci planes staged per round
#define NGRP 8      // ci groups
#define CPG  2      // ci planes computed per group per round
#define ROWS (RG + 2)
#define LW   35     // word0 = left halo, 1..32 = data cols, 33 = right halo, 34 pad
#define WSLICE 64   // floats per (cob,ci) w-slice slot (36 used, 256B aligned)

#define XS_WORDS  (CIC * ROWS * LW)       // 5600 words = 22400 B
#define RED_STRIDE 20                     // words per (group,thread) slot (16 used)
#define RED_WORDS (7 * 64 * RED_STRIDE)   // 8960 words = 35840 B
#define SMEM_WORDS (RED_WORDS > XS_WORDS ? RED_WORDS : XS_WORDS)

// ---- repack: w[co][ci][t] -> wr[(co/4)*64+ci][ (co&3)*9 + t ], 64-f slots ----
__global__ void repack_w(const float* __restrict__ w, float* __restrict__ wr)
{
    int i  = blockIdx.x * 256 + threadIdx.x;   // 4096 = (co,ci) pairs
    int co = i >> 6;
    int ci = i & 63;
    float* dst = wr + (size_t)((co >> 2) * 64 + ci) * WSLICE + (co & 3) * 9;
    const float* src = w + (size_t)co * (CI_ * 9) + ci * 9;
#pragma unroll
    for (int t = 0; t < 9; ++t) dst[t] = src[t];
}

__global__ __launch_bounds__(512, 4) void adder2d_kernel(
    const float* __restrict__ x, const float* __restrict__ wr,
    float* __restrict__ out)
{
    __shared__ __align__(16) float smem[SMEM_WORDS];
    float (*xs)[ROWS][LW] = (float (*)[ROWS][LW])smem;   // phase A
    // phase B (aliases xs after barrier): slot (g,t) at ((g*64+t)*RED_STRIDE)

    const int tid = threadIdx.x;
    const int u   = tid & 7;             // col-quad: pixels at cols 4u..4u+3
    const int rl  = (tid >> 3) & 7;      // pixel row within block
    const int cig = tid >> 6;            // ci group: 0..7 (uniform per wave)
    const int r0  = blockIdx.x * RG;
    const int co0 = blockIdx.y * COB;
    const int n   = blockIdx.z;

    // wave-uniform group index -> provably scalar w pointer (s_load path)
    const int cigs = __builtin_amdgcn_readfirstlane(cig);
    const float* wrb = wr + (size_t)blockIdx.y * 64 * WSLICE;

    // ---- zero xs once: halo words (0,33) and OOB row slots stay zero ----
    for (int i = tid; i < XS_WORDS / 4; i += 512)
        ((float4*)smem)[i] = float4{0.f, 0.f, 0.f, 0.f};

    float acc[PX][CG];
#pragma unroll
    for (int i = 0; i < PX; ++i)
#pragma unroll
        for (int j = 0; j < CG; ++j) acc[i][j] = 0.f;

    const float* xn = x + (size_t)n * CI_ * HW_ * HW_;
    const int pbase = cig * CPG;

    for (int round = 0; round < CI_ / CIC; ++round) {
        const int cc0 = round * CIC;
        __syncthreads();   // protect LDS from previous round's readers
        // ---- stage CIC planes, rows r0-1..r0+8: 1280 float4 units ----
        for (int i = tid; i < CIC * ROWS * (HW_ / 4); i += 512) {
            int plane = i / (ROWS * (HW_ / 4));
            int rem   = i - plane * (ROWS * (HW_ / 4));
            int rr    = rem >> 3;
            int f4    = rem & 7;
            int gr    = r0 - 1 + rr;
            if ((unsigned)gr < HW_) {
                float4 v = ((const float4*)(xn + (size_t)(cc0 + plane) * HW_ * HW_
                                            + gr * HW_))[f4];
                float* dst = &xs[plane][rr][1 + 4 * f4];   // data words 1..32
                dst[0] = v.x; dst[1] = v.y; dst[2] = v.z; dst[3] = v.w;
            }
        }
        __syncthreads();

        // ---- ONE batched scalar w load per round: 72 floats, one drain ----
        const float* wu_p = wrb + (size_t)(cc0 + cigs * CPG) * WSLICE;
        float wu0[36], wu1[36];
#pragma unroll
        for (int t = 0; t < 36; ++t) wu0[t] = wu_p[t];
#pragma unroll
        for (int t = 0; t < 36; ++t) wu1[t] = wu_p[WSLICE + t];

#define COMPUTE_CI(PL, WU)                                                    \
        {                                                                     \
            float xr[3][6];                                                   \
            _Pragma("unroll")                                                 \
            for (int kh = 0; kh < 3; ++kh) {                                  \
                const float* row = &xs[PL][rl + kh][4 * u];                   \
                xr[kh][0] = row[0]; xr[kh][1] = row[1]; xr[kh][2] = row[2];   \
                xr[kh][3] = row[3]; xr[kh][4] = row[4]; xr[kh][5] = row[5];   \
            }                                                                 \
            _Pragma("unroll")                                                 \
            for (int kh = 0; kh < 3; ++kh)                                    \
                _Pragma("unroll")                                             \
                for (int kw = 0; kw < 3; ++kw) {                              \
                    const int t = kh * 3 + kw;                                \
                    _Pragma("unroll")                                         \
                    for (int j = 0; j < CG; ++j) {                            \
                        const float wjt = WU[j * 9 + t];                      \
                        _Pragma("unroll")                                     \
                        for (int i = 0; i < PX; ++i)                          \
                            acc[i][j] += fabsf(xr[kh][i + kw] - wjt);         \
                    }                                                         \
                }                                                             \
        }

        COMPUTE_CI(pbase + 0, wu0)
        COMPUTE_CI(pbase + 1, wu1)
#undef COMPUTE_CI
    }

    // ---- combine the eight ci-group partials (red aliases dead xs) ----
    __syncthreads();   // all xs readers done before overwrite
    if (cig != 0) {
        int t = tid & 63;
        float* rp = smem + (size_t)((cig - 1) * 64 + t) * RED_STRIDE;
#pragma unroll
        for (int i = 0; i < PX; ++i)
            *(float4*)&rp[4 * i] = float4{acc[i][0], acc[i][1], acc[i][2], acc[i][3]};
    }
    __syncthreads();
    if (cig == 0) {
#pragma unroll
        for (int g = 0; g < 7; ++g) {
            const float* rp = smem + (size_t)(g * 64 + tid) * RED_STRIDE;
#pragma unroll
            for (int i = 0; i < PX; ++i) {
                float4 r = *(const float4*)&rp[4 * i];
                acc[i][0] += r.x; acc[i][1] += r.y;
                acc[i][2] += r.z; acc[i][3] += r.w;
            }
        }
        float* op = out + (((size_t)n * CO_ + co0) * HW_ + (r0 + rl)) * HW_ + 4 * u;
#pragma unroll
        for (int j = 0; j < CG; ++j)
            *(float4*)&op[(size_t)j * HW_ * HW_] =
                float4{-acc[0][j], -acc[1][j], -acc[2][j], -acc[3][j]};
    }
}

extern "C" void kernel_launch(void* const* d_in, const int* in_sizes, int n_in,
                              void* d_out, int out_size, void* d_ws, size_t ws_size,
                              hipStream_t stream) {
    const float* x  = (const float*)d_in[0];
    const float* wp = (const float*)d_in[1];
    float* out      = (float*)d_out;
    float* wr       = (float*)d_ws;   // 16*64*64*4 = 256 KiB used

    repack_w<<<dim3(16), 256, 0, stream>>>(wp, wr);
    dim3 grid(HW_ / RG, CO_ / COB, N_);   // (4, 16, 16) = 1024 blocks
    adder2d_kernel<<<grid, 512, 0, stream>>>(x, wr, out);
}